// Round 1
// baseline (412.873 us; speedup 1.0000x reference)
//
#include <hip/hip_runtime.h>

// LocallyLowRank: N=4, A=16, H=W=384, 8x8 blocks stride 4 -> NB=95.
// For each of 4*95*95 = 36100 blocks: m = 64x16 matrix (P=64 pixels x A=16 ch),
// SVD soft-threshold (tau=2):  m' = m * Phi,  Phi = V diag(max(s-2,0)/s) V^T
// where G = m^T m = V diag(s^2) V^T.  Then scatter-add m' and divide by weights.
//
// Eigensolve: ONE-SIDED (Hestenes) Jacobi on G (16x16). For symmetric PSD G,
// right-rotations orthogonalizing G's columns give W = G V with w_k = lam_k v_k:
// column norms = eigenvalues, directions = eigenvectors. No V tracking, no row
// rotations, no dynamic register indexing. Phi = sum_k rho_k w_k w_k^T with
// rho_k = max(1 - 2/sqrt(lam),0)/lam^2  (lam = ||w_k||).
//
// Layout: 1 wave per WG, 4 matrices per wave, 16 lanes per matrix
// (lane = column). Partner pulls via __shfl_xor(width=16); pair schedule =
// xor masks m=1..15 (all 120 pairs per sweep), 5 sweeps.

#define N_      4
#define A_      16
#define H_      384
#define W_      384
#define PLANE_  (H_*W_)       // 147456
#define NB_     95
#define NBB_    (NB_*NB_)     // 9025
#define NMAT_   (N_*NBB_)     // 36100
#define NSWEEP_ 5

__global__ __launch_bounds__(64, 4)
void llr_main(const float* __restrict__ x, float* __restrict__ out) {
    // Mt: staged matrix, TRANSPOSED: Mt[a][p] = M[p][a]. Row stride 68 floats
    //     (=272B, 16B aligned; breaks pow2 bank stride).
    // Gl: per-group 16x16 matrix as columns, col stride 20 floats, group
    //     stride 324 floats (group skew of 4 banks kills 4-way conflicts on
    //     the broadcast reads). Slot [col*20+16] holds rho in the W phase.
    // Gl is reused 3x: G columns -> W columns(+rho) -> Phi columns.
    __shared__ __align__(16) float Mt[16][68];
    __shared__ __align__(16) float Gl[4][324];

    const int lane = threadIdx.x;   // 0..63
    const int g    = lane >> 4;     // matrix slot within wave
    const int j    = lane & 15;     // column index within matrix
    const int wg   = blockIdx.x;    // 0..9024

    const int pr = lane >> 3;       // patch row (staging/final: lane = pixel)
    const int pc = lane & 7;        // patch col

    const int jj  = lane & 15;      // Gram: G row handled by this lane
    const int kq4 = (lane >> 4) * 4;// Gram: 4-column group handled

    // ---------------- Phase 1: stage + Gram, 4 matrices sequentially --------
    for (int s = 0; s < 4; ++s) {
        const int id  = wg * 4 + s;
        const int n   = id / NBB_;
        const int rem = id % NBB_;
        const int bi  = rem / NB_;
        const int bj  = rem % NB_;
        const int base = n * (A_ * PLANE_) + (bi*4 + pr) * W_ + (bj*4 + pc);

        __syncthreads();  // protect Mt from previous iteration's readers
        #pragma unroll
        for (int a = 0; a < 16; ++a)
            Mt[a][lane] = x[base + a * PLANE_];   // coalesced global, cf-free LDS
        __syncthreads();

        // G[jj][kq4+i] = sum_p Mt[jj][p] * Mt[kq4+i][p]; b-reads are 16-lane
        // broadcasts, a-read is 16 distinct addrs x4 dup (2-way conflict, free).
        float a0 = 0.f, a1 = 0.f, a2 = 0.f, a3 = 0.f;
        #pragma unroll
        for (int p = 0; p < 64; p += 4) {
            const float4 av = *(const float4*)&Mt[jj][p];
            const float4 b0 = *(const float4*)&Mt[kq4 + 0][p];
            const float4 b1 = *(const float4*)&Mt[kq4 + 1][p];
            const float4 b2 = *(const float4*)&Mt[kq4 + 2][p];
            const float4 b3 = *(const float4*)&Mt[kq4 + 3][p];
            a0 += av.x*b0.x + av.y*b0.y + av.z*b0.z + av.w*b0.w;
            a1 += av.x*b1.x + av.y*b1.y + av.z*b1.z + av.w*b1.w;
            a2 += av.x*b2.x + av.y*b2.y + av.z*b2.z + av.w*b2.w;
            a3 += av.x*b3.x + av.y*b3.y + av.z*b3.z + av.w*b3.w;
        }
        // G symmetric: row jj stored as column jj.
        *(float4*)&Gl[s][jj*20 + kq4] = make_float4(a0, a1, a2, a3);
    }
    __syncthreads();

    // ---------------- Phase 2: read my column into registers ----------------
    float w[16];
    {
        const float4 t0 = *(const float4*)&Gl[g][j*20 + 0];
        const float4 t1 = *(const float4*)&Gl[g][j*20 + 4];
        const float4 t2 = *(const float4*)&Gl[g][j*20 + 8];
        const float4 t3 = *(const float4*)&Gl[g][j*20 + 12];
        w[0]=t0.x; w[1]=t0.y; w[2]=t0.z; w[3]=t0.w;
        w[4]=t1.x; w[5]=t1.y; w[6]=t1.z; w[7]=t1.w;
        w[8]=t2.x; w[9]=t2.y; w[10]=t2.z; w[11]=t2.w;
        w[12]=t3.x; w[13]=t3.y; w[14]=t3.z; w[15]=t3.w;
    }
    float nrm = 0.f;   // ||w_j||^2, maintained analytically per rotation
    #pragma unroll
    for (int i = 0; i < 16; ++i) nrm += w[i] * w[i];

    // ---------------- Phase 3: one-sided Jacobi (register-resident) ---------
    for (int sweep = 0; sweep < NSWEEP_; ++sweep) {
        for (int m = 1; m < 16; ++m) {          // xor tournament: all 120 pairs
            float pw[16];
            #pragma unroll
            for (int i = 0; i < 16; ++i) pw[i] = __shfl_xor(w[i], m, 16);
            const float pn = __shfl_xor(nrm, m, 16);

            float gam = 0.f;                    // w_p . w_q (identical in pair)
            #pragma unroll
            for (int i = 0; i < 16; ++i) gam += w[i] * pw[i];

            const bool  low = ((j ^ m) > j);    // exactly one member is low
            const float na  = low ? nrm : pn;   // canonical (low,high) order so
            const float nb  = low ? pn  : nrm;  // both lanes get identical c,s

            const float thr = 1e-12f * (na + nb);
            const bool  rot = fabsf(gam) > thr;
            const float gs  = rot ? gam : 1.f;
            const float zeta = (nb - na) / (2.f * gs);
            float t = copysignf(1.f, zeta) / (fabsf(zeta) + sqrtf(1.f + zeta*zeta));
            float c = rsqrtf(1.f + t*t);
            float sv = c * t;
            if (!rot) { c = 1.f; sv = 0.f; }

            const float ss = low ? -sv : sv;    // low: c*w - s*pw ; high: c*w + s*pw
            #pragma unroll
            for (int i = 0; i < 16; ++i) w[i] = c*w[i] + ss*pw[i];

            const float cc = c*c, s2 = sv*sv, x2 = 2.f*c*sv*gam;
            nrm = low ? (cc*na + s2*nb - x2) : (s2*na + cc*nb + x2);
        }
    }
    // exact norm (removes 75-round analytic drift)
    nrm = 0.f;
    #pragma unroll
    for (int i = 0; i < 16; ++i) nrm += w[i] * w[i];

    // rho = max(1 - 2/sigma, 0)/lam^2 ; lam = sqrt(nrm), sigma = sqrt(lam).
    // sigma<=2 (lam^2<=16) -> 0, which also kills noise directions of tiny lam.
    float rho = 0.f;
    if (nrm > 16.f) {
        const float lam = sqrtf(nrm);
        const float sig = sqrtf(lam);
        rho = (1.f - 2.f / sig) / nrm;
    }

    __syncthreads();
    // write W columns + rho back into Gl
    *(float4*)&Gl[g][j*20 + 0]  = make_float4(w[0], w[1], w[2], w[3]);
    *(float4*)&Gl[g][j*20 + 4]  = make_float4(w[4], w[5], w[6], w[7]);
    *(float4*)&Gl[g][j*20 + 8]  = make_float4(w[8], w[9], w[10], w[11]);
    *(float4*)&Gl[g][j*20 + 12] = make_float4(w[12], w[13], w[14], w[15]);
    Gl[g][j*20 + 16] = rho;
    __syncthreads();

    // ---------------- Phase 4: Phi column j = sum_k (rho_k w_k[j]) w_k ------
    float phi[16];
    #pragma unroll
    for (int i = 0; i < 16; ++i) phi[i] = 0.f;
    #pragma unroll
    for (int k = 0; k < 16; ++k) {
        const float coef = Gl[g][k*20 + 16] * Gl[g][k*20 + j];
        const float4 c0 = *(const float4*)&Gl[g][k*20 + 0];
        const float4 c1 = *(const float4*)&Gl[g][k*20 + 4];
        const float4 c2 = *(const float4*)&Gl[g][k*20 + 8];
        const float4 c3 = *(const float4*)&Gl[g][k*20 + 12];
        phi[0]+=coef*c0.x; phi[1]+=coef*c0.y; phi[2]+=coef*c0.z; phi[3]+=coef*c0.w;
        phi[4]+=coef*c1.x; phi[5]+=coef*c1.y; phi[6]+=coef*c1.z; phi[7]+=coef*c1.w;
        phi[8]+=coef*c2.x; phi[9]+=coef*c2.y; phi[10]+=coef*c2.z; phi[11]+=coef*c2.w;
        phi[12]+=coef*c3.x; phi[13]+=coef*c3.y; phi[14]+=coef*c3.z; phi[15]+=coef*c3.w;
    }
    __syncthreads();               // all reads of W done -> overwrite with Phi
    *(float4*)&Gl[g][j*20 + 0]  = make_float4(phi[0], phi[1], phi[2], phi[3]);
    *(float4*)&Gl[g][j*20 + 4]  = make_float4(phi[4], phi[5], phi[6], phi[7]);
    *(float4*)&Gl[g][j*20 + 8]  = make_float4(phi[8], phi[9], phi[10], phi[11]);
    *(float4*)&Gl[g][j*20 + 12] = make_float4(phi[12], phi[13], phi[14], phi[15]);
    __syncthreads();

    // ---------------- Phase 5: out += M * Phi (lane = pixel) ----------------
    // Phi symmetric, so reading "column k" gives row k: o[a] += M[p][k]*Phi[k][a].
    for (int s = 0; s < 4; ++s) {
        const int id  = wg * 4 + s;
        const int n   = id / NBB_;
        const int rem = id % NBB_;
        const int bi  = rem / NB_;
        const int bj  = rem % NB_;
        const int base = n * (A_ * PLANE_) + (bi*4 + pr) * W_ + (bj*4 + pc);

        float mr[16];
        #pragma unroll
        for (int a = 0; a < 16; ++a) mr[a] = x[base + a * PLANE_];  // L2-hot reload

        float o[16];
        #pragma unroll
        for (int a = 0; a < 16; ++a) o[a] = 0.f;
        #pragma unroll
        for (int k = 0; k < 16; ++k) {
            const float mk = mr[k];
            const float4 f0 = *(const float4*)&Gl[s][k*20 + 0];   // uniform addr:
            const float4 f1 = *(const float4*)&Gl[s][k*20 + 4];   // pure broadcast
            const float4 f2 = *(const float4*)&Gl[s][k*20 + 8];
            const float4 f3 = *(const float4*)&Gl[s][k*20 + 12];
            o[0]+=mk*f0.x;  o[1]+=mk*f0.y;  o[2]+=mk*f0.z;  o[3]+=mk*f0.w;
            o[4]+=mk*f1.x;  o[5]+=mk*f1.y;  o[6]+=mk*f1.z;  o[7]+=mk*f1.w;
            o[8]+=mk*f2.x;  o[9]+=mk*f2.y;  o[10]+=mk*f2.z; o[11]+=mk*f2.w;
            o[12]+=mk*f3.x; o[13]+=mk*f3.y; o[14]+=mk*f3.z; o[15]+=mk*f3.w;
        }
        // native fp32 fadd atomics (unsafeAtomicAdd -> global_atomic_add_f32);
        // contention is only ~4 blocks/address.
        #pragma unroll
        for (int a = 0; a < 16; ++a)
            unsafeAtomicAdd(&out[base + a * PLANE_], o[a]);
    }
}

// out /= block_weights (broadcast over the N*A=64 planes)
__global__ __launch_bounds__(256)
void llr_div(float* __restrict__ out, const float* __restrict__ bw) {
    const int i = (blockIdx.x * 256 + threadIdx.x) * 4;   // grid sized exactly
    float4 o = *(float4*)&out[i];
    const float4 b = *(const float4*)&bw[i % PLANE_];     // PLANE_%4==0 -> aligned
    o.x /= b.x; o.y /= b.y; o.z /= b.z; o.w /= b.w;
    *(float4*)&out[i] = o;
}

extern "C" void kernel_launch(void* const* d_in, const int* in_sizes, int n_in,
                              void* d_out, int out_size, void* d_ws, size_t ws_size,
                              hipStream_t stream) {
    (void)in_sizes; (void)n_in; (void)d_ws; (void)ws_size;
    const float* x  = (const float*)d_in[0];
    const float* bw = (const float*)d_in[1];
    float* out = (float*)d_out;

    // harness poisons d_out with 0xAA before every launch -> zero it ourselves
    hipMemsetAsync(out, 0, (size_t)out_size * sizeof(float), stream);

    hipLaunchKernelGGL(llr_main, dim3(NMAT_ / 4), dim3(64), 0, stream, x, out);
    hipLaunchKernelGGL(llr_div,  dim3((N_*A_*PLANE_) / (256*4)), dim3(256), 0, stream, out, bw);
}